// Round 9
// baseline (2765.788 us; speedup 1.0000x reference)
//
#include <hip/hip_runtime.h>
#include <cstdint>
#include <cstddef>

// ---------------------------------------------------------------------------
// HamiltonianFlowModel: flow_fwd -> RK4(grad_H @ M^T) -> flow_inv
// R9: rk4 = 16 samples x 256 threads (4 waves, 64 cols/wave), sequential
//     T-then-V phases (R5 order), LDS 22.8 KB (under the 32KB residency
//     granule) -> 5-7 blocks/CU. Native bf16 casts; bf16 gHT/gHV fused
//     into the final M-multiply.
// ---------------------------------------------------------------------------

namespace {
constexpr int kDim = 64;   // DIM
constexpr int kQd  = 32;   // DIM/2
constexpr int kNl  = 6;    // NLAYERS
constexpr float kDt = 0.05f;

// ws layout (u16 element offsets)
constexpr size_t oKW1  = 0;        // [256][64]
constexpr size_t oKW1T = 16384;    // [64][256]
constexpr size_t oKW2  = 32768;    // [256][256]
constexpr size_t oKW2T = 98304;    // [256][256]
constexpr size_t oVW1  = 163840;   // [256][32]
constexpr size_t oVW1T = 172032;   // [32][256]
constexpr size_t oVW2  = 180224;   // [256][256]
constexpr size_t oVW2T = 245760;   // [256][256]
constexpr size_t oMb   = 311296;   // [64][64]
constexpr size_t oSW1  = 315392;   // [6][128][32]
constexpr size_t oTW1  = 339968;   // [6][128][32]
constexpr size_t oSW2  = 364544;   // [6][32][128]
constexpr size_t oTW2  = 389120;   // [6][32][128]
}

typedef unsigned short u16;
typedef float  f32x4 __attribute__((ext_vector_type(4)));
typedef __bf16 b16x8 __attribute__((ext_vector_type(8)));

// ---------------- helpers (native bf16 casts; HW cvt is RNE) ----------------
__device__ __forceinline__ u16 f2bf(float f) {
  return __builtin_bit_cast(u16, (__bf16)f);
}
__device__ __forceinline__ uint32_t pkbf(float a, float b) {
  return (uint32_t)f2bf(a) | ((uint32_t)f2bf(b) << 16);
}
__device__ __forceinline__ float bf2f(u16 v) {
  return (float)__builtin_bit_cast(__bf16, v);
}
__device__ __forceinline__ f32x4 mfma16(uint4 a, uint4 b, f32x4 c) {
  return __builtin_amdgcn_mfma_f32_16x16x32_bf16(
      __builtin_bit_cast(b16x8, a), __builtin_bit_cast(b16x8, b), c, 0, 0, 0);
}
__device__ __forceinline__ f32x4 ntld4(const float* p) {
  return __builtin_nontemporal_load(reinterpret_cast<const f32x4*>(p));
}
__device__ __forceinline__ void ntst4(float* p, f32x4 v) {
  __builtin_nontemporal_store(v, reinterpret_cast<f32x4*>(p));
}
__device__ __forceinline__ float softplusf(float a) {
  return __logf(1.f + __expf(a));
}
__device__ __forceinline__ float sigmoidf_(float a) {
  return 1.f / (1.f + __expf(-a));
}

// ---------------- prep: bf16 weights (+transposes) and fused M ----------------
__global__ void prep_w(const float* __restrict__ kW1, const float* __restrict__ kW2,
                       const float* __restrict__ vW1, const float* __restrict__ vW2,
                       const float* __restrict__ A,  const float* __restrict__ Lp,
                       const float* __restrict__ sW1, const float* __restrict__ tW1,
                       const float* __restrict__ sW2, const float* __restrict__ tW2,
                       u16* __restrict__ wsb) {
  const int n = blockIdx.x * 256 + threadIdx.x;   // grid = 65536 threads exactly
  {
    u16 v = f2bf(kW2[n]);
    wsb[oKW2 + n] = v;
    wsb[oKW2T + (size_t)(n & 255) * 256 + (n >> 8)] = v;
    u16 w = f2bf(vW2[n]);
    wsb[oVW2 + n] = w;
    wsb[oVW2T + (size_t)(n & 255) * 256 + (n >> 8)] = w;
  }
  if (n < 24576) {
    wsb[oSW1 + n] = f2bf(sW1[n]);
    wsb[oTW1 + n] = f2bf(tW1[n]);
    wsb[oSW2 + n] = f2bf(sW2[n]);
    wsb[oTW2 + n] = f2bf(tW2[n]);
  }
  if (n < 16384) {
    u16 v = f2bf(kW1[n]);
    wsb[oKW1 + n] = v;
    wsb[oKW1T + (size_t)(n & 63) * 256 + (n >> 6)] = v;
  }
  if (n < 8192) {
    u16 v = f2bf(vW1[n]);
    wsb[oVW1 + n] = v;
    wsb[oVW1T + (size_t)(n & 31) * 256 + (n >> 5)] = v;
  }
  if (n < 4096) {  // M = (A - A^T) - L L^T
    int d = n >> 6, e = n & 63;
    int kmax = min(d, e);
    float sum = 0.f;
    for (int k = 0; k <= kmax; ++k) {
      float ld = (k < d) ? Lp[d * kDim + k] : log1pf(expf(Lp[d * kDim + d]));
      float le = (k < e) ? Lp[e * kDim + k] : log1pf(expf(Lp[e * kDim + e]));
      sum += ld * le;
    }
    wsb[oMb + n] = f2bf(A[d * kDim + e] - A[e * kDim + d] - sum);
  }
}

// ---------------- flow (fwd/inv) via MFMA (unchanged) ----------------
template <bool FWD>
__global__ __launch_bounds__(512, 2)
void flow_mfma(const float* __restrict__ io_in, float* __restrict__ io_out,
               const u16* __restrict__ wsb,
               const float* __restrict__ b1s, const float* __restrict__ b2s,
               const float* __restrict__ b1t, const float* __restrict__ b2t) {
  __shared__ __align__(16) float Xs[32][68];     // fp32 state
  __shared__ __align__(16) u16   CondB[32][40];  // bf16 cond half
  __shared__ __align__(16) u16   H1[32][264];    // relu hidden, cols 0-127 s, 128-255 t
  __shared__ __align__(16) float Sv[32][36];
  __shared__ __align__(16) float Tv[32][36];

  const u16* W1s = wsb + oSW1;  // [6][128][32]
  const u16* W1t = wsb + oTW1;
  const u16* W2s = wsb + oSW2;  // [6][32][128]
  const u16* W2t = wsb + oTW2;

  const int tid  = threadIdx.x;
  const int lane = tid & 63, wv = tid >> 6;
  const int r = lane & 15, kg = lane >> 4;
  const size_t base = (size_t)blockIdx.x * 32;
  const int sm = tid >> 4, quad = tid & 15;       // io mapping: 1 float4/thread

  {
    f32x4 v = ntld4(io_in + (base + sm) * kDim + quad * 4);
    *reinterpret_cast<f32x4*>(&Xs[sm][quad * 4]) = v;
  }
  __syncthreads();

#pragma unroll 1
  for (int li = 0; li < kNl; ++li) {
    const int l = FWD ? li : (kNl - 1 - li);
    const int par = l & 1;
    const int cb = par ? kQd : 0;   // cond base col
    const int tb = par ? 0 : kQd;   // transform base col

    { // build bf16 cond
      int idx = tid * 2, s = idx >> 5, c = idx & 31;
      *reinterpret_cast<uint32_t*>(&CondB[s][c]) = pkbf(Xs[s][cb + c], Xs[s][cb + c + 1]);
    }
    __syncthreads();

    { // GEMM1: [32x32] @ W1^T -> relu -> H1 (s-net waves 0-3, t-net waves 4-7)
      const int net = wv >> 2;
      const int nc0 = (wv & 3) * 32;
      const u16* W1 = net ? W1t : W1s;
      const float* b1 = net ? b1t : b1s;
      uint4 b0 = *reinterpret_cast<const uint4*>(W1 + ((size_t)l*128 + nc0 + r) * 32 + kg*8);
      uint4 b1v = *reinterpret_cast<const uint4*>(W1 + ((size_t)l*128 + nc0 + 16 + r) * 32 + kg*8);
      uint4 a0 = *reinterpret_cast<const uint4*>(&CondB[r][kg*8]);
      uint4 a1 = *reinterpret_cast<const uint4*>(&CondB[16 + r][kg*8]);
      f32x4 acc[2][2] = {};
      acc[0][0] = mfma16(a0,b0,acc[0][0]); acc[0][1] = mfma16(a0,b1v,acc[0][1]);
      acc[1][0] = mfma16(a1,b0,acc[1][0]); acc[1][1] = mfma16(a1,b1v,acc[1][1]);
      float bn0 = b1[l*128 + nc0 + r], bn1 = b1[l*128 + nc0 + 16 + r];
      const int colbase = net * 128 + nc0;
#pragma unroll
      for (int mt = 0; mt < 2; ++mt)
#pragma unroll
        for (int reg = 0; reg < 4; ++reg) {
          int row = mt*16 + kg*4 + reg;
          H1[row][colbase + r]      = f2bf(fmaxf(acc[mt][0][reg] + bn0, 0.f));
          H1[row][colbase + 16 + r] = f2bf(fmaxf(acc[mt][1][reg] + bn1, 0.f));
        }
    }
    __syncthreads();

    { // GEMM2: [32x128] @ W2^T -> Sv (tanh+b2s) / Tv (+b2t)
      const int net = wv >> 2, mt = (wv >> 1) & 1, nt2 = wv & 1;
      const u16* W2 = net ? W2t : W2s;
      f32x4 acc = {};
#pragma unroll 2
      for (int kc = 0; kc < 4; ++kc) {
        uint4 a = *reinterpret_cast<const uint4*>(&H1[mt*16 + r][net*128 + kc*32 + kg*8]);
        uint4 b = *reinterpret_cast<const uint4*>(W2 + ((size_t)l*32 + nt2*16 + r) * 128 + kc*32 + kg*8);
        acc = mfma16(a, b, acc);
      }
      if (net == 0) {
        float b2 = b2s[l*32 + nt2*16 + r];
#pragma unroll
        for (int reg = 0; reg < 4; ++reg)
          Sv[mt*16 + kg*4 + reg][nt2*16 + r] = tanhf(acc[reg] + b2);
      } else {
        float b2 = b2t[l*32 + nt2*16 + r];
#pragma unroll
        for (int reg = 0; reg < 4; ++reg)
          Tv[mt*16 + kg*4 + reg][nt2*16 + r] = acc[reg] + b2;
      }
    }
    __syncthreads();

    { // update transformed half
#pragma unroll
      for (int it = 0; it < 2; ++it) {
        int idx = tid + it * 512, s = idx >> 5, d = idx & 31;
        float sv = Sv[s][d], tv = Tv[s][d];
        float x = Xs[s][tb + d];
        Xs[s][tb + d] = FWD ? (x * __expf(sv) + tv) : ((x - tv) * __expf(-sv));
      }
    }
    __syncthreads();
  }

  {
    f32x4 v = *reinterpret_cast<const f32x4*>(&Xs[sm][quad * 4]);
    ntst4(io_out + (base + sm) * kDim + quad * 4, v);
  }
}

// ---------------- RK4 via MFMA: 16 samples, 256 threads (4 waves) ----------
// Wave wv owns output cols [wv*64, wv*64+64) (4 n-tiles x 1 m-tile).
// Sequential phases (R5 order), 10 barriers/eval. LDS 22.8 KB.
//  P1: B1 = softplus(Z @ kW1^T + kb1)
//  P2: B2 = sigmoid(B1 @ kW2^T + kb2) * kW3
//  P3: B1 = (B2 @ kW2) * (1 - exp(-B1))       [in place]
//  P4: gHT = B1 @ kW1            (bf16 [16][72])
//  P5: B1 = softplus(Zq @ vW1^T + vb1)
//  P6: B2 = sigmoid(B1 @ vW2^T + vb2) * vW3
//  P7: B1 = (B2 @ vW2) * (1 - exp(-B1))       [in place]
//  P8: gHV = B1 @ vW1            (bf16 [16][40], waves 0-1)
//  P9: dz = gHT @ M^T + gHV @ M[:, :32]^T -> dzf (f32 over B2)
//  RK: 4 dims/thread state update, Zs rewrite
__global__ __launch_bounds__(256, 5)
void rk4_mfma(float* __restrict__ qp, const float* __restrict__ u,
              const u16* __restrict__ wsb,
              const float* __restrict__ kb1, const float* __restrict__ kb2,
              const float* __restrict__ kW3,
              const float* __restrict__ vb1, const float* __restrict__ vb2,
              const float* __restrict__ vW3,
              const float* __restrict__ Bc) {
  __shared__ __align__(16) u16 Zs[16][72];
  __shared__ __align__(16) u16 B1[16][264];
  __shared__ __align__(16) u16 B2[16][264];
  __shared__ __align__(16) u16 gHT[16][72];
  __shared__ __align__(16) u16 gHV[16][40];
  float* dzf = reinterpret_cast<float*>(&B2[0][0]);  // [16][68] f32 overlay

  const u16* kW1b  = wsb + oKW1;
  const u16* kW1Tb = wsb + oKW1T;
  const u16* kW2b  = wsb + oKW2;
  const u16* kW2Tb = wsb + oKW2T;
  const u16* vW1b  = wsb + oVW1;
  const u16* vW1Tb = wsb + oVW1T;
  const u16* vW2b  = wsb + oVW2;
  const u16* vW2Tb = wsb + oVW2T;
  const u16* Mb    = wsb + oMb;

  const int tid  = threadIdx.x;
  const int lane = tid & 63, wv = tid >> 6;       // wv in 0..3
  const int r = lane & 15, kg = lane >> 4;
  const int n0 = wv * 64;
  const size_t base = (size_t)blockIdx.x * 16;

  // RK state: thread owns sample s=tid>>4 (0..15), dims d0..d0+3
  const int s  = tid >> 4;
  const int d0 = (tid & 15) * 4;
  float qp0[4], accRK[4] = {0.f, 0.f, 0.f, 0.f}, bc4[4];
  {
    f32x4 v = ntld4(qp + (base + s) * kDim + d0);
    qp0[0] = v.x; qp0[1] = v.y; qp0[2] = v.z; qp0[3] = v.w;
  }
  const float u_s = __builtin_nontemporal_load(u + base + s);
#pragma unroll
  for (int i = 0; i < 4; ++i)
    bc4[i] = (d0 + i >= kQd) ? Bc[d0 + i - kQd] : 0.0f;
  *reinterpret_cast<uint2*>(&Zs[s][d0]) =
      make_uint2(pkbf(qp0[0], qp0[1]), pkbf(qp0[2], qp0[3]));
  __syncthreads();

#pragma unroll 1
  for (int ev = 0; ev < 4; ++ev) {
    { // ---- P1: B1 = softplus(Z @ kW1^T + kb1) ----
      f32x4 acc[4] = {};
#pragma unroll
      for (int kc = 0; kc < 2; ++kc) {
        uint4 a = *reinterpret_cast<const uint4*>(&Zs[r][kc*32 + kg*8]);
#pragma unroll
        for (int nt = 0; nt < 4; ++nt) {
          uint4 b = *reinterpret_cast<const uint4*>(kW1b + (size_t)(n0 + nt*16 + r)*64 + kc*32 + kg*8);
          acc[nt] = mfma16(a, b, acc[nt]);
        }
      }
#pragma unroll
      for (int nt = 0; nt < 4; ++nt) {
        const int col = n0 + nt*16 + r;
        float bn = kb1[col];
#pragma unroll
        for (int reg = 0; reg < 4; ++reg)
          B1[kg*4 + reg][col] = f2bf(softplusf(acc[nt][reg] + bn));
      }
    }
    __syncthreads();

    { // ---- P2: B2 = sigmoid(B1 @ kW2^T + kb2) * kW3 ----
      f32x4 acc[4] = {};
#pragma unroll 2
      for (int kc = 0; kc < 8; ++kc) {
        uint4 a = *reinterpret_cast<const uint4*>(&B1[r][kc*32 + kg*8]);
#pragma unroll
        for (int nt = 0; nt < 4; ++nt) {
          uint4 b = *reinterpret_cast<const uint4*>(kW2b + (size_t)(n0 + nt*16 + r)*256 + kc*32 + kg*8);
          acc[nt] = mfma16(a, b, acc[nt]);
        }
      }
#pragma unroll
      for (int nt = 0; nt < 4; ++nt) {
        const int col = n0 + nt*16 + r;
        float bn = kb2[col], w3n = kW3[col];
#pragma unroll
        for (int reg = 0; reg < 4; ++reg)
          B2[kg*4 + reg][col] = f2bf(w3n * sigmoidf_(acc[nt][reg] + bn));
      }
    }
    __syncthreads();

    { // ---- P3: B1 = (B2 @ kW2) * (1 - exp(-B1)) in place ----
      f32x4 acc[4] = {};
#pragma unroll 2
      for (int kc = 0; kc < 8; ++kc) {
        uint4 a = *reinterpret_cast<const uint4*>(&B2[r][kc*32 + kg*8]);
#pragma unroll
        for (int nt = 0; nt < 4; ++nt) {
          uint4 b = *reinterpret_cast<const uint4*>(kW2Tb + (size_t)(n0 + nt*16 + r)*256 + kc*32 + kg*8);
          acc[nt] = mfma16(a, b, acc[nt]);
        }
      }
#pragma unroll
      for (int nt = 0; nt < 4; ++nt) {
        const int col = n0 + nt*16 + r;
#pragma unroll
        for (int reg = 0; reg < 4; ++reg) {
          const int row = kg*4 + reg;
          float h = bf2f(B1[row][col]);
          B1[row][col] = f2bf(acc[nt][reg] * (1.f - __expf(-h)));
        }
      }
    }
    __syncthreads();

    { // ---- P4: gHT = B1 @ kW1 (4 tiles, 1/wave) ----
      f32x4 acc = {};
#pragma unroll 2
      for (int kc = 0; kc < 8; ++kc) {
        uint4 a = *reinterpret_cast<const uint4*>(&B1[r][kc*32 + kg*8]);
        uint4 b = *reinterpret_cast<const uint4*>(kW1Tb + (size_t)(wv*16 + r)*256 + kc*32 + kg*8);
        acc = mfma16(a, b, acc);
      }
#pragma unroll
      for (int reg = 0; reg < 4; ++reg)
        gHT[kg*4 + reg][wv*16 + r] = f2bf(acc[reg]);
    }
    __syncthreads();

    { // ---- P5: B1 = softplus(Zq @ vW1^T + vb1) (K=32) ----
      f32x4 acc[4] = {};
      uint4 a = *reinterpret_cast<const uint4*>(&Zs[r][kg*8]);
#pragma unroll
      for (int nt = 0; nt < 4; ++nt) {
        uint4 b = *reinterpret_cast<const uint4*>(vW1b + (size_t)(n0 + nt*16 + r)*32 + kg*8);
        acc[nt] = mfma16(a, b, acc[nt]);
      }
#pragma unroll
      for (int nt = 0; nt < 4; ++nt) {
        const int col = n0 + nt*16 + r;
        float bn = vb1[col];
#pragma unroll
        for (int reg = 0; reg < 4; ++reg)
          B1[kg*4 + reg][col] = f2bf(softplusf(acc[nt][reg] + bn));
      }
    }
    __syncthreads();

    { // ---- P6: B2 = sigmoid(B1 @ vW2^T + vb2) * vW3 ----
      f32x4 acc[4] = {};
#pragma unroll 2
      for (int kc = 0; kc < 8; ++kc) {
        uint4 a = *reinterpret_cast<const uint4*>(&B1[r][kc*32 + kg*8]);
#pragma unroll
        for (int nt = 0; nt < 4; ++nt) {
          uint4 b = *reinterpret_cast<const uint4*>(vW2b + (size_t)(n0 + nt*16 + r)*256 + kc*32 + kg*8);
          acc[nt] = mfma16(a, b, acc[nt]);
        }
      }
#pragma unroll
      for (int nt = 0; nt < 4; ++nt) {
        const int col = n0 + nt*16 + r;
        float bn = vb2[col], w3n = vW3[col];
#pragma unroll
        for (int reg = 0; reg < 4; ++reg)
          B2[kg*4 + reg][col] = f2bf(w3n * sigmoidf_(acc[nt][reg] + bn));
      }
    }
    __syncthreads();

    { // ---- P7: B1 = (B2 @ vW2) * (1 - exp(-B1)) in place ----
      f32x4 acc[4] = {};
#pragma unroll 2
      for (int kc = 0; kc < 8; ++kc) {
        uint4 a = *reinterpret_cast<const uint4*>(&B2[r][kc*32 + kg*8]);
#pragma unroll
        for (int nt = 0; nt < 4; ++nt) {
          uint4 b = *reinterpret_cast<const uint4*>(vW2Tb + (size_t)(n0 + nt*16 + r)*256 + kc*32 + kg*8);
          acc[nt] = mfma16(a, b, acc[nt]);
        }
      }
#pragma unroll
      for (int nt = 0; nt < 4; ++nt) {
        const int col = n0 + nt*16 + r;
#pragma unroll
        for (int reg = 0; reg < 4; ++reg) {
          const int row = kg*4 + reg;
          float h = bf2f(B1[row][col]);
          B1[row][col] = f2bf(acc[nt][reg] * (1.f - __expf(-h)));
        }
      }
    }
    __syncthreads();

    { // ---- P8: gHV = B1 @ vW1 (2 tiles, waves 0-1) ----
      if (wv < 2) {
        f32x4 acc = {};
#pragma unroll 2
        for (int kc = 0; kc < 8; ++kc) {
          uint4 a = *reinterpret_cast<const uint4*>(&B1[r][kc*32 + kg*8]);
          uint4 b = *reinterpret_cast<const uint4*>(vW1Tb + (size_t)(wv*16 + r)*256 + kc*32 + kg*8);
          acc = mfma16(a, b, acc);
        }
#pragma unroll
        for (int reg = 0; reg < 4; ++reg)
          gHV[kg*4 + reg][wv*16 + r] = f2bf(acc[reg]);
      }
    }
    __syncthreads();

    { // ---- P9: dz = gHT @ M^T + gHV @ M[:, :32]^T -> dzf ----
      f32x4 acc = {};
#pragma unroll
      for (int kc = 0; kc < 2; ++kc) {
        uint4 a = *reinterpret_cast<const uint4*>(&gHT[r][kc*32 + kg*8]);
        uint4 b = *reinterpret_cast<const uint4*>(Mb + (size_t)(wv*16 + r)*64 + kc*32 + kg*8);
        acc = mfma16(a, b, acc);
      }
      {
        uint4 a = *reinterpret_cast<const uint4*>(&gHV[r][kg*8]);
        uint4 b = *reinterpret_cast<const uint4*>(Mb + (size_t)(wv*16 + r)*64 + kg*8);
        acc = mfma16(a, b, acc);
      }
#pragma unroll
      for (int reg = 0; reg < 4; ++reg)
        dzf[(size_t)(kg*4 + reg)*68 + wv*16 + r] = acc[reg];
    }
    __syncthreads();

    { // ---- RK update (4 dims/thread) ----
      const float cstep = (ev == 2) ? kDt : (0.5f * kDt);
      const float wgt   = (ev == 0 || ev == 3) ? 1.0f : 2.0f;
      f32x4 dv = *reinterpret_cast<const f32x4*>(dzf + (size_t)s*68 + d0);
      float vv[4] = {dv.x, dv.y, dv.z, dv.w};
      float zn[4];
#pragma unroll
      for (int i = 0; i < 4; ++i) {
        vv[i] += u_s * bc4[i];
        accRK[i] += wgt * vv[i];
        zn[i] = qp0[i] + cstep * vv[i];
      }
      if (ev < 3)
        *reinterpret_cast<uint2*>(&Zs[s][d0]) =
            make_uint2(pkbf(zn[0], zn[1]), pkbf(zn[2], zn[3]));
    }
    __syncthreads();
  }

  {
    f32x4 v;
#pragma unroll
    for (int i = 0; i < 4; ++i) v[i] = qp0[i] + (kDt / 6.0f) * accRK[i];
    ntst4(qp + (base + s) * kDim + d0, v);
  }
}

// ---------------- host ----------------
extern "C" void kernel_launch(void* const* d_in, const int* in_sizes, int n_in,
                              void* d_out, int out_size, void* d_ws, size_t ws_size,
                              hipStream_t stream) {
  const float* h    = (const float*)d_in[0];
  const float* u    = (const float*)d_in[1];
  const float* sW1  = (const float*)d_in[2];
  const float* sb1  = (const float*)d_in[3];
  const float* sW2  = (const float*)d_in[4];
  const float* sb2  = (const float*)d_in[5];
  const float* tW1  = (const float*)d_in[6];
  const float* tb1  = (const float*)d_in[7];
  const float* tW2  = (const float*)d_in[8];
  const float* tb2  = (const float*)d_in[9];
  const float* kW1  = (const float*)d_in[10];
  const float* kb1  = (const float*)d_in[11];
  const float* kW2  = (const float*)d_in[12];
  const float* kb2  = (const float*)d_in[13];
  const float* kW3  = (const float*)d_in[14];
  const float* vW1  = (const float*)d_in[16];
  const float* vb1  = (const float*)d_in[17];
  const float* vW2  = (const float*)d_in[18];
  const float* vb2  = (const float*)d_in[19];
  const float* vW3  = (const float*)d_in[20];
  const float* A    = (const float*)d_in[22];
  const float* Lp   = (const float*)d_in[23];
  const float* Bc   = (const float*)d_in[24];
  (void)n_in; (void)ws_size; (void)out_size;

  float* out = (float*)d_out;
  u16*   wsb = (u16*)d_ws;

  const int B = in_sizes[0] / kDim;        // 131072
  const int grid32 = B / 32;               // 4096
  const int grid16 = B / 16;               // 8192

  prep_w<<<256, 256, 0, stream>>>(kW1, kW2, vW1, vW2, A, Lp, sW1, tW1, sW2, tW2, wsb);
  flow_mfma<true><<<grid32, 512, 0, stream>>>(h, out, wsb, sb1, sb2, tb1, tb2);
  rk4_mfma<<<grid16, 256, 0, stream>>>(out, u, wsb, kb1, kb2, kW3,
                                       vb1, vb2, vW3, Bc);
  flow_mfma<false><<<grid32, 512, 0, stream>>>(out, out, wsb, sb1, sb2, tb1, tb2);
}

// Round 10
// 1571.783 us; speedup vs baseline: 1.7597x; 1.7597x over previous
//
#include <hip/hip_runtime.h>
#include <cstdint>
#include <cstddef>

// ---------------------------------------------------------------------------
// HamiltonianFlowModel: flow_fwd -> RK4(grad_H @ M^T) -> flow_inv
// R10: revert to the proven R5 skeleton (512 thr / 32 samples / sequential
//      phases / launch_bounds(512,2)) + two R6-proven epilogue grafts:
//      native __bf16 casts, and bf16 gHT/gHV with V-grad fused into P9.
// ---------------------------------------------------------------------------

namespace {
constexpr int kDim = 64;   // DIM
constexpr int kQd  = 32;   // DIM/2
constexpr int kNl  = 6;    // NLAYERS
constexpr float kDt = 0.05f;

// ws layout (u16 element offsets)
constexpr size_t oKW1  = 0;        // [256][64]
constexpr size_t oKW1T = 16384;    // [64][256]
constexpr size_t oKW2  = 32768;    // [256][256]
constexpr size_t oKW2T = 98304;    // [256][256]
constexpr size_t oVW1  = 163840;   // [256][32]
constexpr size_t oVW1T = 172032;   // [32][256]
constexpr size_t oVW2  = 180224;   // [256][256]
constexpr size_t oVW2T = 245760;   // [256][256]
constexpr size_t oMb   = 311296;   // [64][64]
constexpr size_t oSW1  = 315392;   // [6][128][32]
constexpr size_t oTW1  = 339968;   // [6][128][32]
constexpr size_t oSW2  = 364544;   // [6][32][128]
constexpr size_t oTW2  = 389120;   // [6][32][128]
}

typedef unsigned short u16;
typedef float  f32x4 __attribute__((ext_vector_type(4)));
typedef __bf16 b16x8 __attribute__((ext_vector_type(8)));

// ---------------- helpers (native bf16 casts; HW cvt is RNE) ----------------
__device__ __forceinline__ u16 f2bf(float f) {
  return __builtin_bit_cast(u16, (__bf16)f);
}
__device__ __forceinline__ uint32_t pkbf(float a, float b) {
  return (uint32_t)f2bf(a) | ((uint32_t)f2bf(b) << 16);
}
__device__ __forceinline__ float bf2f(u16 v) {
  return (float)__builtin_bit_cast(__bf16, v);
}
__device__ __forceinline__ f32x4 mfma16(uint4 a, uint4 b, f32x4 c) {
  return __builtin_amdgcn_mfma_f32_16x16x32_bf16(
      __builtin_bit_cast(b16x8, a), __builtin_bit_cast(b16x8, b), c, 0, 0, 0);
}
__device__ __forceinline__ f32x4 ntld4(const float* p) {
  return __builtin_nontemporal_load(reinterpret_cast<const f32x4*>(p));
}
__device__ __forceinline__ void ntst4(float* p, f32x4 v) {
  __builtin_nontemporal_store(v, reinterpret_cast<f32x4*>(p));
}
__device__ __forceinline__ float softplusf(float a) {
  return __logf(1.f + __expf(a));
}
__device__ __forceinline__ float sigmoidf_(float a) {
  return 1.f / (1.f + __expf(-a));
}

// ---------------- prep: bf16 weights (+transposes) and fused M ----------------
__global__ void prep_w(const float* __restrict__ kW1, const float* __restrict__ kW2,
                       const float* __restrict__ vW1, const float* __restrict__ vW2,
                       const float* __restrict__ A,  const float* __restrict__ Lp,
                       const float* __restrict__ sW1, const float* __restrict__ tW1,
                       const float* __restrict__ sW2, const float* __restrict__ tW2,
                       u16* __restrict__ wsb) {
  const int n = blockIdx.x * 256 + threadIdx.x;   // grid = 65536 threads exactly
  {
    u16 v = f2bf(kW2[n]);
    wsb[oKW2 + n] = v;
    wsb[oKW2T + (size_t)(n & 255) * 256 + (n >> 8)] = v;
    u16 w = f2bf(vW2[n]);
    wsb[oVW2 + n] = w;
    wsb[oVW2T + (size_t)(n & 255) * 256 + (n >> 8)] = w;
  }
  if (n < 24576) {
    wsb[oSW1 + n] = f2bf(sW1[n]);
    wsb[oTW1 + n] = f2bf(tW1[n]);
    wsb[oSW2 + n] = f2bf(sW2[n]);
    wsb[oTW2 + n] = f2bf(tW2[n]);
  }
  if (n < 16384) {
    u16 v = f2bf(kW1[n]);
    wsb[oKW1 + n] = v;
    wsb[oKW1T + (size_t)(n & 63) * 256 + (n >> 6)] = v;
  }
  if (n < 8192) {
    u16 v = f2bf(vW1[n]);
    wsb[oVW1 + n] = v;
    wsb[oVW1T + (size_t)(n & 31) * 256 + (n >> 5)] = v;
  }
  if (n < 4096) {  // M = (A - A^T) - L L^T
    int d = n >> 6, e = n & 63;
    int kmax = min(d, e);
    float sum = 0.f;
    for (int k = 0; k <= kmax; ++k) {
      float ld = (k < d) ? Lp[d * kDim + k] : log1pf(expf(Lp[d * kDim + d]));
      float le = (k < e) ? Lp[e * kDim + k] : log1pf(expf(Lp[e * kDim + e]));
      sum += ld * le;
    }
    wsb[oMb + n] = f2bf(A[d * kDim + e] - A[e * kDim + d] - sum);
  }
}

// ---------------- flow (fwd/inv) via MFMA (R5 structure, native casts) -------
template <bool FWD>
__global__ __launch_bounds__(512, 2)
void flow_mfma(const float* __restrict__ io_in, float* __restrict__ io_out,
               const u16* __restrict__ wsb,
               const float* __restrict__ b1s, const float* __restrict__ b2s,
               const float* __restrict__ b1t, const float* __restrict__ b2t) {
  __shared__ __align__(16) float Xs[32][68];     // fp32 state
  __shared__ __align__(16) u16   CondB[32][40];  // bf16 cond half
  __shared__ __align__(16) u16   H1[32][264];    // relu hidden, cols 0-127 s, 128-255 t
  __shared__ __align__(16) float Sv[32][36];
  __shared__ __align__(16) float Tv[32][36];

  const u16* W1s = wsb + oSW1;  // [6][128][32]
  const u16* W1t = wsb + oTW1;
  const u16* W2s = wsb + oSW2;  // [6][32][128]
  const u16* W2t = wsb + oTW2;

  const int tid  = threadIdx.x;
  const int lane = tid & 63, wv = tid >> 6;
  const int r = lane & 15, kg = lane >> 4;
  const size_t base = (size_t)blockIdx.x * 32;
  const int sm = tid >> 4, quad = tid & 15;       // io mapping: 1 float4/thread

  {
    f32x4 v = ntld4(io_in + (base + sm) * kDim + quad * 4);
    *reinterpret_cast<f32x4*>(&Xs[sm][quad * 4]) = v;
  }
  __syncthreads();

#pragma unroll 1
  for (int li = 0; li < kNl; ++li) {
    const int l = FWD ? li : (kNl - 1 - li);
    const int par = l & 1;
    const int cb = par ? kQd : 0;   // cond base col
    const int tb = par ? 0 : kQd;   // transform base col

    { // build bf16 cond
      int idx = tid * 2, s = idx >> 5, c = idx & 31;
      *reinterpret_cast<uint32_t*>(&CondB[s][c]) = pkbf(Xs[s][cb + c], Xs[s][cb + c + 1]);
    }
    __syncthreads();

    { // GEMM1: [32x32] @ W1^T -> relu -> H1 (s-net waves 0-3, t-net waves 4-7)
      const int net = wv >> 2;
      const int nc0 = (wv & 3) * 32;
      const u16* W1 = net ? W1t : W1s;
      const float* b1 = net ? b1t : b1s;
      uint4 b0 = *reinterpret_cast<const uint4*>(W1 + ((size_t)l*128 + nc0 + r) * 32 + kg*8);
      uint4 b1v = *reinterpret_cast<const uint4*>(W1 + ((size_t)l*128 + nc0 + 16 + r) * 32 + kg*8);
      uint4 a0 = *reinterpret_cast<const uint4*>(&CondB[r][kg*8]);
      uint4 a1 = *reinterpret_cast<const uint4*>(&CondB[16 + r][kg*8]);
      f32x4 acc[2][2] = {};
      acc[0][0] = mfma16(a0,b0,acc[0][0]); acc[0][1] = mfma16(a0,b1v,acc[0][1]);
      acc[1][0] = mfma16(a1,b0,acc[1][0]); acc[1][1] = mfma16(a1,b1v,acc[1][1]);
      float bn0 = b1[l*128 + nc0 + r], bn1 = b1[l*128 + nc0 + 16 + r];
      const int colbase = net * 128 + nc0;
#pragma unroll
      for (int mt = 0; mt < 2; ++mt)
#pragma unroll
        for (int reg = 0; reg < 4; ++reg) {
          int row = mt*16 + kg*4 + reg;
          H1[row][colbase + r]      = f2bf(fmaxf(acc[mt][0][reg] + bn0, 0.f));
          H1[row][colbase + 16 + r] = f2bf(fmaxf(acc[mt][1][reg] + bn1, 0.f));
        }
    }
    __syncthreads();

    { // GEMM2: [32x128] @ W2^T -> Sv (tanh+b2s) / Tv (+b2t)
      const int net = wv >> 2, mt = (wv >> 1) & 1, nt2 = wv & 1;
      const u16* W2 = net ? W2t : W2s;
      f32x4 acc = {};
#pragma unroll 2
      for (int kc = 0; kc < 4; ++kc) {
        uint4 a = *reinterpret_cast<const uint4*>(&H1[mt*16 + r][net*128 + kc*32 + kg*8]);
        uint4 b = *reinterpret_cast<const uint4*>(W2 + ((size_t)l*32 + nt2*16 + r) * 128 + kc*32 + kg*8);
        acc = mfma16(a, b, acc);
      }
      if (net == 0) {
        float b2 = b2s[l*32 + nt2*16 + r];
#pragma unroll
        for (int reg = 0; reg < 4; ++reg)
          Sv[mt*16 + kg*4 + reg][nt2*16 + r] = tanhf(acc[reg] + b2);
      } else {
        float b2 = b2t[l*32 + nt2*16 + r];
#pragma unroll
        for (int reg = 0; reg < 4; ++reg)
          Tv[mt*16 + kg*4 + reg][nt2*16 + r] = acc[reg] + b2;
      }
    }
    __syncthreads();

    { // update transformed half
#pragma unroll
      for (int it = 0; it < 2; ++it) {
        int idx = tid + it * 512, s = idx >> 5, d = idx & 31;
        float sv = Sv[s][d], tv = Tv[s][d];
        float x = Xs[s][tb + d];
        Xs[s][tb + d] = FWD ? (x * __expf(sv) + tv) : ((x - tv) * __expf(-sv));
      }
    }
    __syncthreads();
  }

  {
    f32x4 v = *reinterpret_cast<const f32x4*>(&Xs[sm][quad * 4]);
    ntst4(io_out + (base + sm) * kDim + quad * 4, v);
  }
}

// ---------------- RK4 via MFMA (R5 skeleton + bf16 gHT/gHV + fused P9) -----
// 512 threads = 8 waves, 32 samples. Per 256-wide GEMM: wave w owns cols
// [w*32, w*32+32): 2 m-tiles x 2 n-tiles.
// LDS: Zs 4.5K + B1 16.5K + B2 16.5K + gHT 4.5K + gHV 2.5K = 44.5 KB.
__device__ __forceinline__ void gemm256_2x2(const u16* __restrict__ Ab, int lda,
                                            const u16* __restrict__ Wb,
                                            int r, int kg, int n0, f32x4 acc[2][2]) {
#pragma unroll 2
  for (int kc = 0; kc < 8; ++kc) {
    uint4 b0 = *reinterpret_cast<const uint4*>(Wb + (size_t)(n0 + r) * 256 + kc*32 + kg*8);
    uint4 b1 = *reinterpret_cast<const uint4*>(Wb + (size_t)(n0 + 16 + r) * 256 + kc*32 + kg*8);
    uint4 a0 = *reinterpret_cast<const uint4*>(Ab + (size_t)r * lda + kc*32 + kg*8);
    uint4 a1 = *reinterpret_cast<const uint4*>(Ab + (size_t)(16 + r) * lda + kc*32 + kg*8);
    acc[0][0] = mfma16(a0, b0, acc[0][0]); acc[0][1] = mfma16(a0, b1, acc[0][1]);
    acc[1][0] = mfma16(a1, b0, acc[1][0]); acc[1][1] = mfma16(a1, b1, acc[1][1]);
  }
}

__global__ __launch_bounds__(512, 2)
void rk4_mfma(float* __restrict__ qp, const float* __restrict__ u,
              const u16* __restrict__ wsb,
              const float* __restrict__ kb1, const float* __restrict__ kb2,
              const float* __restrict__ kW3,
              const float* __restrict__ vb1, const float* __restrict__ vb2,
              const float* __restrict__ vW3,
              const float* __restrict__ Bc) {
  __shared__ __align__(16) u16 Zs[32][72];
  __shared__ __align__(16) u16 B1[32][264];
  __shared__ __align__(16) u16 B2[32][264];
  __shared__ __align__(16) u16 gHT[32][72];
  __shared__ __align__(16) u16 gHV[32][40];
  float* dzf = reinterpret_cast<float*>(&B2[0][0]);  // f32 [32][68] overlay (B2 dead after P7)

  const u16* kW1b  = wsb + oKW1;
  const u16* kW1Tb = wsb + oKW1T;
  const u16* kW2b  = wsb + oKW2;
  const u16* kW2Tb = wsb + oKW2T;
  const u16* vW1b  = wsb + oVW1;
  const u16* vW1Tb = wsb + oVW1T;
  const u16* vW2b  = wsb + oVW2;
  const u16* vW2Tb = wsb + oVW2T;
  const u16* Mb    = wsb + oMb;

  const int tid  = threadIdx.x;
  const int lane = tid & 63, wv = tid >> 6;
  const int r = lane & 15, kg = lane >> 4;
  const int n0 = wv * 32;
  const size_t base = (size_t)blockIdx.x * 32;

  const int s  = tid >> 4;
  const int d0 = (tid & 15) * 4;
  float qp0[4], accRK[4] = {0.f, 0.f, 0.f, 0.f}, bc4[4];
  {
    f32x4 v = ntld4(qp + (base + s) * kDim + d0);
    qp0[0] = v.x; qp0[1] = v.y; qp0[2] = v.z; qp0[3] = v.w;
  }
  const float u_s = __builtin_nontemporal_load(u + base + s);
#pragma unroll
  for (int i = 0; i < 4; ++i)
    bc4[i] = (d0 + i >= kQd) ? Bc[d0 + i - kQd] : 0.0f;
  *reinterpret_cast<uint2*>(&Zs[s][d0]) =
      make_uint2(pkbf(qp0[0], qp0[1]), pkbf(qp0[2], qp0[3]));
  __syncthreads();

#pragma unroll 1
  for (int ev = 0; ev < 4; ++ev) {
    { // P1: B1 = softplus(Z @ kW1^T + kb1)
      f32x4 acc[2][2] = {};
#pragma unroll
      for (int kc = 0; kc < 2; ++kc) {
        uint4 b0 = *reinterpret_cast<const uint4*>(kW1b + (size_t)(n0 + r) * 64 + kc*32 + kg*8);
        uint4 b1 = *reinterpret_cast<const uint4*>(kW1b + (size_t)(n0 + 16 + r) * 64 + kc*32 + kg*8);
        uint4 a0 = *reinterpret_cast<const uint4*>(&Zs[r][kc*32 + kg*8]);
        uint4 a1 = *reinterpret_cast<const uint4*>(&Zs[16 + r][kc*32 + kg*8]);
        acc[0][0] = mfma16(a0,b0,acc[0][0]); acc[0][1] = mfma16(a0,b1,acc[0][1]);
        acc[1][0] = mfma16(a1,b0,acc[1][0]); acc[1][1] = mfma16(a1,b1,acc[1][1]);
      }
      float bn0 = kb1[n0 + r], bn1 = kb1[n0 + 16 + r];
#pragma unroll
      for (int mt = 0; mt < 2; ++mt)
#pragma unroll
        for (int reg = 0; reg < 4; ++reg) {
          int row = mt*16 + kg*4 + reg;
          B1[row][n0 + r]      = f2bf(softplusf(acc[mt][0][reg] + bn0));
          B1[row][n0 + 16 + r] = f2bf(softplusf(acc[mt][1][reg] + bn1));
        }
    }
    __syncthreads();

    { // P2: B2 = sigmoid(B1 @ kW2^T + kb2) * kW3
      f32x4 acc[2][2] = {};
      gemm256_2x2(&B1[0][0], 264, kW2b, r, kg, n0, acc);
      float bn0 = kb2[n0 + r], bn1 = kb2[n0 + 16 + r];
      float w30 = kW3[n0 + r], w31 = kW3[n0 + 16 + r];
#pragma unroll
      for (int mt = 0; mt < 2; ++mt)
#pragma unroll
        for (int reg = 0; reg < 4; ++reg) {
          int row = mt*16 + kg*4 + reg;
          B2[row][n0 + r]      = f2bf(w30 * sigmoidf_(acc[mt][0][reg] + bn0));
          B2[row][n0 + 16 + r] = f2bf(w31 * sigmoidf_(acc[mt][1][reg] + bn1));
        }
    }
    __syncthreads();

    { // P3: B1 = (B2 @ kW2) * (1 - exp(-B1)) in place
      f32x4 acc[2][2] = {};
      gemm256_2x2(&B2[0][0], 264, kW2Tb, r, kg, n0, acc);
#pragma unroll
      for (int mt = 0; mt < 2; ++mt)
#pragma unroll
        for (int nt = 0; nt < 2; ++nt)
#pragma unroll
          for (int reg = 0; reg < 4; ++reg) {
            int row = mt*16 + kg*4 + reg, col = n0 + nt*16 + r;
            float h = bf2f(B1[row][col]);
            B1[row][col] = f2bf(acc[mt][nt][reg] * (1.f - __expf(-h)));
          }
    }
    __syncthreads();

    { // P4: gHT = B1 @ kW1  (8 tiles, 1 per wave; bf16 out)
      const int mt = wv >> 2, nt = wv & 3;
      f32x4 acc = {};
#pragma unroll 2
      for (int kc = 0; kc < 8; ++kc) {
        uint4 b = *reinterpret_cast<const uint4*>(kW1Tb + (size_t)(nt*16 + r) * 256 + kc*32 + kg*8);
        uint4 a = *reinterpret_cast<const uint4*>(&B1[mt*16 + r][kc*32 + kg*8]);
        acc = mfma16(a, b, acc);
      }
#pragma unroll
      for (int reg = 0; reg < 4; ++reg)
        gHT[mt*16 + kg*4 + reg][nt*16 + r] = f2bf(acc[reg]);
    }
    __syncthreads();

    { // P5: B1 = softplus(Zq @ vW1^T + vb1)   (K=32)
      f32x4 acc[2][2] = {};
      uint4 b0 = *reinterpret_cast<const uint4*>(vW1b + (size_t)(n0 + r) * 32 + kg*8);
      uint4 b1 = *reinterpret_cast<const uint4*>(vW1b + (size_t)(n0 + 16 + r) * 32 + kg*8);
      uint4 a0 = *reinterpret_cast<const uint4*>(&Zs[r][kg*8]);
      uint4 a1 = *reinterpret_cast<const uint4*>(&Zs[16 + r][kg*8]);
      acc[0][0] = mfma16(a0,b0,acc[0][0]); acc[0][1] = mfma16(a0,b1,acc[0][1]);
      acc[1][0] = mfma16(a1,b0,acc[1][0]); acc[1][1] = mfma16(a1,b1,acc[1][1]);
      float bn0 = vb1[n0 + r], bn1 = vb1[n0 + 16 + r];
#pragma unroll
      for (int mt = 0; mt < 2; ++mt)
#pragma unroll
        for (int reg = 0; reg < 4; ++reg) {
          int row = mt*16 + kg*4 + reg;
          B1[row][n0 + r]      = f2bf(softplusf(acc[mt][0][reg] + bn0));
          B1[row][n0 + 16 + r] = f2bf(softplusf(acc[mt][1][reg] + bn1));
        }
    }
    __syncthreads();

    { // P6: B2 = sigmoid(B1 @ vW2^T + vb2) * vW3
      f32x4 acc[2][2] = {};
      gemm256_2x2(&B1[0][0], 264, vW2b, r, kg, n0, acc);
      float bn0 = vb2[n0 + r], bn1 = vb2[n0 + 16 + r];
      float w30 = vW3[n0 + r], w31 = vW3[n0 + 16 + r];
#pragma unroll
      for (int mt = 0; mt < 2; ++mt)
#pragma unroll
        for (int reg = 0; reg < 4; ++reg) {
          int row = mt*16 + kg*4 + reg;
          B2[row][n0 + r]      = f2bf(w30 * sigmoidf_(acc[mt][0][reg] + bn0));
          B2[row][n0 + 16 + r] = f2bf(w31 * sigmoidf_(acc[mt][1][reg] + bn1));
        }
    }
    __syncthreads();

    { // P7: B1 = (B2 @ vW2) * (1 - exp(-B1)) in place
      f32x4 acc[2][2] = {};
      gemm256_2x2(&B2[0][0], 264, vW2Tb, r, kg, n0, acc);
#pragma unroll
      for (int mt = 0; mt < 2; ++mt)
#pragma unroll
        for (int nt = 0; nt < 2; ++nt)
#pragma unroll
          for (int reg = 0; reg < 4; ++reg) {
            int row = mt*16 + kg*4 + reg, col = n0 + nt*16 + r;
            float h = bf2f(B1[row][col]);
            B1[row][col] = f2bf(acc[mt][nt][reg] * (1.f - __expf(-h)));
          }
    }
    __syncthreads();

    if (wv < 4) { // P8: gHV = B1 @ vW1 (4 tiles, waves 0-3; bf16 out)
      const int mt = wv >> 1, nt = wv & 1;
      f32x4 acc = {};
#pragma unroll 2
      for (int kc = 0; kc < 8; ++kc) {
        uint4 b = *reinterpret_cast<const uint4*>(vW1Tb + (size_t)(nt*16 + r) * 256 + kc*32 + kg*8);
        uint4 a = *reinterpret_cast<const uint4*>(&B1[mt*16 + r][kc*32 + kg*8]);
        acc = mfma16(a, b, acc);
      }
#pragma unroll
      for (int reg = 0; reg < 4; ++reg)
        gHV[mt*16 + kg*4 + reg][nt*16 + r] = f2bf(acc[reg]);
    }
    __syncthreads();

    { // P9: dz = gHT @ M^T + gHV @ M[:, :32]^T -> dzf
      const int mt = wv >> 2, nt = wv & 3;
      f32x4 acc = {};
#pragma unroll
      for (int kc = 0; kc < 2; ++kc) {
        uint4 a = *reinterpret_cast<const uint4*>(&gHT[mt*16 + r][kc*32 + kg*8]);
        uint4 b = *reinterpret_cast<const uint4*>(Mb + (size_t)(nt*16 + r) * 64 + kc*32 + kg*8);
        acc = mfma16(a, b, acc);
      }
      {
        uint4 a = *reinterpret_cast<const uint4*>(&gHV[mt*16 + r][kg*8]);
        uint4 b = *reinterpret_cast<const uint4*>(Mb + (size_t)(nt*16 + r) * 64 + kg*8);
        acc = mfma16(a, b, acc);
      }
#pragma unroll
      for (int reg = 0; reg < 4; ++reg)
        dzf[(size_t)(mt*16 + kg*4 + reg) * 68 + nt*16 + r] = acc[reg];
    }
    __syncthreads();

    { // RK update
      const float cstep = (ev == 2) ? kDt : (0.5f * kDt);
      const float wgt   = (ev == 0 || ev == 3) ? 1.0f : 2.0f;
      float4 dv = *reinterpret_cast<const float4*>(dzf + (size_t)s * 68 + d0);
      float vv[4] = {dv.x, dv.y, dv.z, dv.w};
      float zn[4];
#pragma unroll
      for (int i = 0; i < 4; ++i) {
        vv[i] += u_s * bc4[i];
        accRK[i] += wgt * vv[i];
        zn[i] = qp0[i] + cstep * vv[i];
      }
      if (ev < 3)
        *reinterpret_cast<uint2*>(&Zs[s][d0]) =
            make_uint2(pkbf(zn[0], zn[1]), pkbf(zn[2], zn[3]));
    }
    __syncthreads();
  }

  {
    f32x4 v;
#pragma unroll
    for (int i = 0; i < 4; ++i) v[i] = qp0[i] + (kDt / 6.0f) * accRK[i];
    ntst4(qp + (base + s) * kDim + d0, v);
  }
}

// ---------------- host ----------------
extern "C" void kernel_launch(void* const* d_in, const int* in_sizes, int n_in,
                              void* d_out, int out_size, void* d_ws, size_t ws_size,
                              hipStream_t stream) {
  const float* h    = (const float*)d_in[0];
  const float* u    = (const float*)d_in[1];
  const float* sW1  = (const float*)d_in[2];
  const float* sb1  = (const float*)d_in[3];
  const float* sW2  = (const float*)d_in[4];
  const float* sb2  = (const float*)d_in[5];
  const float* tW1  = (const float*)d_in[6];
  const float* tb1  = (const float*)d_in[7];
  const float* tW2  = (const float*)d_in[8];
  const float* tb2  = (const float*)d_in[9];
  const float* kW1  = (const float*)d_in[10];
  const float* kb1  = (const float*)d_in[11];
  const float* kW2  = (const float*)d_in[12];
  const float* kb2  = (const float*)d_in[13];
  const float* kW3  = (const float*)d_in[14];
  const float* vW1  = (const float*)d_in[16];
  const float* vb1  = (const float*)d_in[17];
  const float* vW2  = (const float*)d_in[18];
  const float* vb2  = (const float*)d_in[19];
  const float* vW3  = (const float*)d_in[20];
  const float* A    = (const float*)d_in[22];
  const float* Lp   = (const float*)d_in[23];
  const float* Bc   = (const float*)d_in[24];
  (void)n_in; (void)ws_size; (void)out_size;

  float* out = (float*)d_out;
  u16*   wsb = (u16*)d_ws;

  const int B = in_sizes[0] / kDim;        // 131072
  const int grid32 = B / 32;               // 4096

  prep_w<<<256, 256, 0, stream>>>(kW1, kW2, vW1, vW2, A, Lp, sW1, tW1, sW2, tW2, wsb);
  flow_mfma<true><<<grid32, 512, 0, stream>>>(h, out, wsb, sb1, sb2, tb1, tb2);
  rk4_mfma<<<grid32, 512, 0, stream>>>(out, u, wsb, kb1, kb2, kW3,
                                       vb1, vb2, vW3, Bc);
  flow_mfma<false><<<grid32, 512, 0, stream>>>(out, out, wsb, sb1, sb2, tb1, tb2);
}